// Round 4
// baseline (147.660 us; speedup 1.0000x reference)
//
#include <hip/hip_runtime.h>
#include <math.h>

#define T_LEN 2000
#define NSTEP3 666          // 1 + 3*666 = 1999 = last emission index

// 1-step in-edge sources per destination (for the alpha_1 bootstrap).
__device__ const int SRC_TBL[24][4] = {
    {0,-1,-1,-1},{0,-1,-1,-1},{1,-1,-1,-1},{2,-1,-1,-1},
    {3,16,-1,-1},{4,-1,-1,-1},{5,-1,-1,-1},{6,19, 3,-1},
    {7,-1,-1,-1},{8,-1,-1,-1},{9,22, 3, 6},{10,-1,-1,-1},
    {11,-1,-1,-1},{12,13,-1,-1},{3,16,-1,-1},{14,-1,-1,-1},
    {15,-1,-1,-1},{6,19,-1,-1},{17,-1,-1,-1},{18,-1,-1,-1},
    {9,22,-1,-1},{20,-1,-1,-1},{21,-1,-1,-1},{13,23,-1,-1}
};

// 3-step slot sources per destination (max 4 distinct sources; -1 unused).
__device__ const int SRC3[24][4] = {
    {0,-1,-1,-1},{0,-1,-1,-1},{0,-1,-1,-1},{0,-1,-1,-1},
    {1,14,-1,-1},{2,15,-1,-1},{3,16,-1,-1},
    {1,4,17,-1},{2,5,18,-1},{3,6,19,-1},
    {1,4,7,20},{2,5,8,21},{3,6,9,22},{10,11,12,13},
    {1,14,-1,-1},{2,15,-1,-1},{3,16,-1,-1},
    {4,17,-1,-1},{5,18,-1,-1},{6,19,-1,-1},
    {7,20,-1,-1},{8,21,-1,-1},{9,22,-1,-1},
    {11,12,13,23}
};

// 3-step path terms per (dest, slot): up to 3 terms of (i, m1, m2); i=-1 empty.
// weight(tuple) = sum_terms A[i][m1]*A[m1][m2]*A[m2][j] * E1[m1] * E2[m2].
// (60 paths total; only j=23 has multi-term slots.)
#define ET {-1,0,0}
__device__ const int TERM3[24][4][3][3] = {
 /* 0*/ {{{0,0,0},ET,ET},{ET,ET,ET},{ET,ET,ET},{ET,ET,ET}},
 /* 1*/ {{{0,0,0},ET,ET},{ET,ET,ET},{ET,ET,ET},{ET,ET,ET}},
 /* 2*/ {{{0,0,1},ET,ET},{ET,ET,ET},{ET,ET,ET},{ET,ET,ET}},
 /* 3*/ {{{0,1,2},ET,ET},{ET,ET,ET},{ET,ET,ET},{ET,ET,ET}},
 /* 4*/ {{{1,2,3},ET,ET},{{14,15,16},ET,ET},{ET,ET,ET},{ET,ET,ET}},
 /* 5*/ {{{2,3,4},ET,ET},{{15,16,4},ET,ET},{ET,ET,ET},{ET,ET,ET}},
 /* 6*/ {{{3,4,5},ET,ET},{{16,4,5},ET,ET},{ET,ET,ET},{ET,ET,ET}},
 /* 7*/ {{{1,2,3},ET,ET},{{4,5,6},ET,ET},{{17,18,19},ET,ET},{ET,ET,ET}},
 /* 8*/ {{{2,3,7},ET,ET},{{5,6,7},ET,ET},{{18,19,7},ET,ET},{ET,ET,ET}},
 /* 9*/ {{{3,7,8},ET,ET},{{6,7,8},ET,ET},{{19,7,8},ET,ET},{ET,ET,ET}},
 /*10*/ {{{1,2,3},ET,ET},{{4,5,6},ET,ET},{{7,8,9},ET,ET},{{20,21,22},ET,ET}},
 /*11*/ {{{2,3,10},ET,ET},{{5,6,10},ET,ET},{{8,9,10},ET,ET},{{21,22,10},ET,ET}},
 /*12*/ {{{3,10,11},ET,ET},{{6,10,11},ET,ET},{{9,10,11},ET,ET},{{22,10,11},ET,ET}},
 /*13*/ {{{10,11,12},ET,ET},{{11,12,13},ET,ET},{{12,13,13},ET,ET},{{13,13,13},ET,ET}},
 /*14*/ {{{1,2,3},ET,ET},{{14,15,16},ET,ET},{ET,ET,ET},{ET,ET,ET}},
 /*15*/ {{{2,3,14},ET,ET},{{15,16,14},ET,ET},{ET,ET,ET},{ET,ET,ET}},
 /*16*/ {{{3,14,15},ET,ET},{{16,14,15},ET,ET},{ET,ET,ET},{ET,ET,ET}},
 /*17*/ {{{4,5,6},ET,ET},{{17,18,19},ET,ET},{ET,ET,ET},{ET,ET,ET}},
 /*18*/ {{{5,6,17},ET,ET},{{18,19,17},ET,ET},{ET,ET,ET},{ET,ET,ET}},
 /*19*/ {{{6,17,18},ET,ET},{{19,17,18},ET,ET},{ET,ET,ET},{ET,ET,ET}},
 /*20*/ {{{7,8,9},ET,ET},{{20,21,22},ET,ET},{ET,ET,ET},{ET,ET,ET}},
 /*21*/ {{{8,9,20},ET,ET},{{21,22,20},ET,ET},{ET,ET,ET},{ET,ET,ET}},
 /*22*/ {{{9,20,21},ET,ET},{{22,20,21},ET,ET},{ET,ET,ET},{ET,ET,ET}},
 /*23*/ {{{11,12,13},ET,ET},
         {{12,13,13},{12,13,23},ET},
         {{13,13,13},{13,13,23},{13,23,23}},
         {{23,23,23},ET,ET}}
};
#undef ET

__device__ __forceinline__ float bperm(int addr_bytes, float v) {
    return __int_as_float(__builtin_amdgcn_ds_bpermute(addr_bytes, __float_as_int(v)));
}

__global__ __launch_bounds__(256, 1) void hmm_fwd_kernel(
        const float* __restrict__ tk,   // transition_kernel (240)
        const float* __restrict__ ek,   // emission_kernel (1088)
        const float* __restrict__ ik,   // init_kernel (24)
        const int*   __restrict__ seq,  // (nseq, 2000)
        float*       __restrict__ out,  // (nseq,)
        int nseq)
{
    __shared__ float As[24][24];                 // softmaxed transition matrix
    __shared__ float Bs[64][24];                 // interior emission [ctx4][state]
    __shared__ __align__(16) float PtW3[24672];  // [256 tuples][24 j][4 slots] + zero row
    __shared__ float APRE[288];                  // 216*A-products per (j,slot,term)
    __shared__ unsigned short rp16s[8][704];     // per-seq packed (tuple | ro<<8)
    __shared__ float piS[24];

    const int tid = threadIdx.x;

    // ---- P1: base fills ----
    if (tid < 24) {
        #pragma unroll
        for (int c = 0; c < 24; ++c) As[tid][c] = -1e30f;
    }
    for (int i = tid; i < 64 * 24; i += 256) (&Bs[0][0])[i] = (1.0f / 6.0f);
    if (tid < 96) PtW3[24576 + tid] = 0.0f;      // zero row for inert lanes
    __syncthreads();

    // ---- P2: sparse A entries, Bem softmax, pi, context-stream build ----
    if (tid == 0) {
        float w0=tk[0], w1=tk[1], w2=tk[2], w3=tk[3], w4=tk[4], w5=tk[5],
              w6=tk[6], w7=tk[7], w8=tk[8], w9=tk[9], w10=tk[10], w11=tk[11],
              w12=tk[12];
        As[0][0]=1.f-w0;  As[0][1]=w0;
        As[1][2]=1.f;     As[2][3]=1.f;
        As[3][4]=w1;      As[6][7]=w2;
        As[4][5]=1.f;     As[7][8]=1.f;
        As[5][6]=1.f;     As[8][9]=1.f;
        As[3][14]=w3;     As[6][17]=w4;    As[9][20]=w5;
        As[9][10]=1.f-w5;
        As[14][15]=1.f;   As[17][18]=1.f;  As[20][21]=1.f;
        As[15][16]=1.f;   As[18][19]=1.f;  As[21][22]=1.f;
        As[16][4]=w6;     As[19][7]=w7;    As[22][10]=w8;
        As[16][14]=1.f-w9; As[19][17]=1.f-w10; As[22][20]=1.f-w11;
        As[3][7]=1.f-w12*w12; As[3][10]=1.f-w12*w12*w12; As[6][10]=1.f-w12*w12;
        As[10][11]=1.f;   As[11][12]=1.f;  As[12][13]=1.f;
        As[13][13]=1.f;   As[13][23]=1.f;
        As[23][23]=1.f;
    }
    for (int r = tid; r < 272; r += 256) {   // 17 states x 16 (pp,p) contexts
        int s = r >> 4, pp = (r >> 2) & 3, p = r & 3;
        const float* e4 = ek + (((s * 4 + pp) * 4 + p) * 4);
        float e0 = e4[0], e1 = e4[1], e2 = e4[2], e3 = e4[3];
        float m = fmaxf(fmaxf(e0, e1), fmaxf(e2, e3));
        float x0 = expf(e0 - m), x1 = expf(e1 - m), x2 = expf(e2 - m), x3 = expf(e3 - m);
        float inv = 1.0f / (x0 + x1 + x2 + x3);
        int base = pp * 16 + p * 4;
        Bs[base + 0][s] = x0 * inv; Bs[base + 1][s] = x1 * inv;
        Bs[base + 2][s] = x2 * inv; Bs[base + 3][s] = x3 * inv;
    }
    if (tid == 255) {
        float m = -1e30f;
        for (int q = 0; q < 24; ++q) m = fmaxf(m, ik[q]);
        float ssum = 0.f;
        for (int q = 0; q < 24; ++q) { float x = expf(ik[q] - m); piS[q] = x; ssum += x; }
        float inv = 1.0f / ssum;
        for (int q = 0; q < 24; ++q) piS[q] *= inv;
    }
    // packed stream: step q covers window s[3q..3q+4]:
    //   lo = tuple(s3q,s3q+1,s3q+2,s3q+3); hi = ctx4(s3q+2,s3q+3,s3q+4)
    for (int i2 = tid; i2 < 8 * 704; i2 += 256) {
        int s = i2 / 704, q = i2 - s * 704;
        int bidx = blockIdx.x * 8 + s;
        if (bidx >= nseq) bidx = nseq - 1;
        unsigned short v = 0;
        if (q < NSTEP3) {
            const int* sp = seq + bidx * T_LEN + 3 * q;
            int a = sp[0], b = sp[1], c = sp[2], d = sp[3], e = sp[4];
            int lo = ((a * 4 + b) * 4 + c) * 4 + d;
            int hi = (c * 4 + d) * 4 + e;
            v = (unsigned short)(lo | (hi << 8));
        }
        rp16s[s][q] = v;
    }
    __syncthreads();

    // ---- P3: row softmax of A (off-structure -> exactly 0) ----
    if (tid < 24) {
        float m = -1e30f;
        #pragma unroll
        for (int c = 0; c < 24; ++c) m = fmaxf(m, As[tid][c]);
        float ssum = 0.f;
        #pragma unroll
        for (int c = 0; c < 24; ++c) { float x = expf(As[tid][c] - m); As[tid][c] = x; ssum += x; }
        float inv = 1.0f / ssum;
        #pragma unroll
        for (int c = 0; c < 24; ++c) As[tid][c] *= inv;
    }
    __syncthreads();

    // ---- P4: 216 * A-products per (j,slot,term) ----
    for (int i2 = tid; i2 < 288; i2 += 256) {
        int jj = i2 / 12, r = i2 - jj * 12, sl = r / 3, tm = r - sl * 3;
        int i = TERM3[jj][sl][tm][0];
        int m1 = TERM3[jj][sl][tm][1], m2 = TERM3[jj][sl][tm][2];
        APRE[i2] = (i >= 0) ? 216.0f * As[i][m1] * As[m1][m2] * As[m2][jj] : 0.0f;
    }
    __syncthreads();

    // ---- P5: fused weight table PtW3[tuple][j][slot] ----
    for (int i2 = tid; i2 < 24576; i2 += 256) {
        int tup = i2 >> 7 << 1 | 0;               // i2/96: compute exactly below
        tup = i2 / 96;
        int rem = i2 - tup * 96;
        int jj = rem >> 2, sl = rem & 3;
        int abc = tup >> 2, bcd = tup & 63;
        float acc = 0.f;
        #pragma unroll
        for (int tm = 0; tm < 3; ++tm) {
            int m1 = TERM3[jj][sl][tm][1], m2 = TERM3[jj][sl][tm][2];
            acc += APRE[(jj * 4 + sl) * 3 + tm] * Bs[abc][m1] * Bs[bcd][m2];
        }
        PtW3[i2] = acc;
    }
    __syncthreads();

    // ---- per-lane setup ----
    const int lane  = threadIdx.x & 63;
    const int gl    = threadIdx.x & 31;
    const int gbase = lane & 32;
    const int j     = gl;
    const int sj    = (j < 24) ? j : 23;
    const int tmask = (j < 24) ? -1 : 0;
    const float* PjW = &PtW3[(j < 24) ? j * 4 : 24576];

    int x0i = gbase*4, x1i = gbase*4, x2i = gbase*4, x3i = gbase*4;
    if (j < 24) {
        int s0 = SRC3[j][0], s1 = SRC3[j][1], s2 = SRC3[j][2], s3 = SRC3[j][3];
        if (s0 >= 0) x0i = (gbase + s0) * 4;
        if (s1 >= 0) x1i = (gbase + s1) * 4;
        if (s2 >= 0) x2i = (gbase + s2) * 4;
        if (s3 >= 0) x3i = (gbase + s3) * 4;
    }

    int b = blockIdx.x * 8 + (tid >> 5);
    const int borig = b;
    if (b >= nseq) b = nseq - 1;

    // alpha_1 closed form: E_0 = E_1 = 1/6 uniformly (start contexts)
    float alpha = 0.f;
    if (j < 24) {
        float p1 = 0.f;
        int s0 = SRC_TBL[j][0], s1 = SRC_TBL[j][1], s2 = SRC_TBL[j][2], s3 = SRC_TBL[j][3];
        if (s0>=0) p1 += As[s0][j]*piS[s0];
        if (s1>=0) p1 += As[s1][j]*piS[s1];
        if (s2>=0) p1 += As[s2][j]*piS[s2];
        if (s3>=0) p1 += As[s3][j]*piS[s3];
        alpha = p1 * ((1.0f/6.0f) * (1.0f/6.0f));
    }

    const unsigned short* rpq = &rp16s[tid >> 5][0];
    float4 WA, WB; float EoA, EoB;
    {
        int v0 = rpq[0], v1 = rpq[1];
        int t0 = (v0 & 255) & tmask, t1 = (v1 & 255) & tmask;
        WA = *(const float4*)(PjW + t0 * 96); EoA = Bs[(v0 >> 8) & 255][sj];
        WB = *(const float4*)(PjW + t1 * 96); EoB = Bs[(v1 >> 8) & 255][sj];
    }
    unsigned short vA = rpq[2], vB = rpq[3];

    double llsum = 0.0;
    float snap = 1.0f / 32.0f;    // sentinel -> chunk-0 divisor = 1.0
    float bfA = 0.f, zP = 1.0f, rzP = 1.0f, lgP = 0.f;

    // One fused iteration: alpha_t -> alpha_{t+3} (t = 1+3q), weights premultiplied
    // per 4-symbol tuple; x216 compensation folded into PtW3. RR: delayed-norm stage.
#define STEP3(Wr, Eor, Vr, RR, QOFF) do {                                      \
    float g0_=bperm(x0i,alpha), g1_=bperm(x1i,alpha);                          \
    float g2_=bperm(x2i,alpha), g3_=bperm(x3i,alpha);                          \
    float a_ = ((Wr.x*g0_ + Wr.y*g1_) + (Wr.z*g2_ + Wr.w*g3_)) * Eor;          \
    { int tup_ = ((int)(Vr) & 255) & tmask;                                    \
      int ro_  = ((int)(Vr) >> 8) & 255;                                       \
      Wr  = *(const float4*)(PjW + tup_ * 96);                                 \
      Eor = Bs[ro_][sj]; }                                                     \
    Vr = rpq[(QOFF)];                                                          \
    if (RR==6) bfA = snap + __shfl_xor(snap,1,32);                             \
    if (RR==5) bfA = bfA + __shfl_xor(bfA,2,32);                               \
    if (RR==4) bfA = bfA + __shfl_xor(bfA,4,32);                               \
    if (RR==3) bfA = bfA + __shfl_xor(bfA,8,32);                               \
    if (RR==2) zP  = bfA + __shfl_xor(bfA,16,32);                              \
    if (RR==1) { rzP = 1.0f/zP; lgP = __log2f(zP); }                           \
    if (RR==0) { a_ *= rzP; llsum += (double)lgP; snap = a_; }                 \
    alpha = a_;                                                                \
} while(0)

    // 666 = 41 x 16 + 10; rescale once per 16 fused steps (mass compensated).
    #pragma unroll 1
    for (int cc = 0; cc < 41; ++cc) {
        STEP3(WA,EoA,vA, 9, 4);  STEP3(WB,EoB,vB, 6, 5);
        STEP3(WA,EoA,vA, 9, 6);  STEP3(WB,EoB,vB, 5, 7);
        STEP3(WA,EoA,vA, 9, 8);  STEP3(WB,EoB,vB, 4, 9);
        STEP3(WA,EoA,vA, 9,10);  STEP3(WB,EoB,vB, 3,11);
        STEP3(WA,EoA,vA, 9,12);  STEP3(WB,EoB,vB, 2,13);
        STEP3(WA,EoA,vA, 9,14);  STEP3(WB,EoB,vB, 1,15);
        STEP3(WA,EoA,vA, 9,16);  STEP3(WB,EoB,vB, 9,17);
        STEP3(WA,EoA,vA, 9,18);  STEP3(WB,EoB,vB, 0,19);
        rpq += 16;
    }
    // tail: 10 steps (q = 656..665 -> alpha_1999); max stream read = rpq[13] -> abs 669
    STEP3(WA,EoA,vA, 6, 4);  STEP3(WB,EoB,vB, 5, 5);
    STEP3(WA,EoA,vA, 4, 6);  STEP3(WB,EoB,vB, 3, 7);
    STEP3(WA,EoA,vA, 2, 8);  STEP3(WB,EoB,vB, 1, 9);
    STEP3(WA,EoA,vA, 9,10);  STEP3(WB,EoB,vB, 9,11);
    STEP3(WA,EoA,vA, 9,12);  STEP3(WB,EoB,vB, 0,13);

    // final mass; undo the per-step x216: subtract 666*ln(216) = 1998*ln(6)
    float zf = alpha;
    zf += __shfl_xor(zf, 1, 32);
    zf += __shfl_xor(zf, 2, 32);
    zf += __shfl_xor(zf, 4, 32);
    zf += __shfl_xor(zf, 8, 32);
    zf += __shfl_xor(zf, 16, 32);
    double ll = (llsum + (double)__log2f(zf)) * 0.6931471805599453
              - 1998.0 * 1.7917594692280550;
    if (gl == 0 && borig < nseq) out[b] = (float)ll;
}

extern "C" void kernel_launch(void* const* d_in, const int* in_sizes, int n_in,
                              void* d_out, int out_size, void* d_ws, size_t ws_size,
                              hipStream_t stream) {
    const float* tk  = (const float*)d_in[0];
    const float* ek  = (const float*)d_in[1];
    const float* ik  = (const float*)d_in[2];
    const int*   seq = (const int*)d_in[3];
    float* out = (float*)d_out;
    (void)d_ws; (void)ws_size;

    int nseq = in_sizes[3] / T_LEN;        // 2048
    int nblocks = (nseq + 7) / 8;          // 8 sequences per 256-thread block
    hipLaunchKernelGGL(hmm_fwd_kernel, dim3(nblocks), dim3(256), 0, stream,
                       tk, ek, ik, seq, out, nseq);
}